// Round 8
// baseline (222.148 us; speedup 1.0000x reference)
//
#include <hip/hip_runtime.h>

// ---------------------------------------------------------------------------
// VanillaSFNN: x[256,1000,700] -> currents GEMM -> LIF spikes -> readout leaky
// integrator + softmax accumulation.
//
// Pipeline (4 launches):
//   k0 wprep  : W_h f32 -> split bf16 hi/lo packed in MFMA fragment order (BK=64)
//   k1 gemm   : BM=64/BK=64 3-term split-bf16 MFMA; x+W staged via
//               global_load_lds ring-2, counted vmcnt(8); 2 blocks/CU.
//               cur written in t-quad layout [r/4][h][4].
//   k2 lif    : chunked speculative scan; lane=h loads f32x4 = 4 t-steps
//   k3 readout: per-batch fused scan, 512 thr, TC=5/NC=200, parallel carry
// ---------------------------------------------------------------------------

typedef float  f32x4  __attribute__((ext_vector_type(4)));
typedef short  short8 __attribute__((ext_vector_type(8)));
typedef unsigned long long ull;

#define B_   256
#define T_   1000
#define K_   700
#define H_   64
#define O_   20
#define NKT  11          // ceil(700/64) k-tiles of BK=64
#define NCH  200         // v_ro chunks
#define TCH  5           // chunk length (NCH*TCH = T_)
#define TCL  100         // LIF chunk length
#define NCL  10          // LIF chunks
#define BIL  40          // LIF burn-in steps

// workspace layout (bytes)
#define OFF_WFRAG  ((size_t)0)            // 11*16384 = 180,224
#define OFF_CUR    ((size_t)262144)       // 256000*64*4 = 65,536,000
#define OFF_MASK   ((size_t)65798144)     // 256000*8    =  2,048,000

// ---------------------------------------------------------------------------
// k0: pack W_h into fragment-ordered split-bf16 (BK=64 tiles, zero-pad k>=700).
// Tile kt (16KB): hi 8KB then lo 8KB. Slot s = (nf*2+kf)*64+lane holds 8 bf16:
// h = nf*16+(lane&15), k = kt*64 + kf*32 + ((lane>>4)&3)*8 + j.
// ---------------------------------------------------------------------------
__global__ void wprep(const float* __restrict__ Wh, unsigned short* __restrict__ wfrag) {
    int e = blockIdx.x * 256 + threadIdx.x;          // 22*256 = 5632 exact
    int kt   = e >> 9;
    int rem  = e & 511;
    int nf   = rem >> 7;
    int kf   = (rem >> 6) & 1;
    int lane = rem & 63;
    int h     = nf * 16 + (lane & 15);
    int kbase = kt * 64 + kf * 32 + ((lane >> 4) & 3) * 8;
    int slot  = (nf * 2 + kf) * 64 + lane;
    unsigned short* dh = wfrag + (size_t)kt * 8192 + slot * 8;
    unsigned short* dl = dh + 4096;
#pragma unroll
    for (int j = 0; j < 8; ++j) {
        int k = kbase + j;
        float v = (k < K_) ? Wh[(size_t)h * K_ + k] : 0.0f;
        unsigned u  = __builtin_bit_cast(unsigned, v);
        float    fh = __builtin_bit_cast(float, u & 0xffff0000u);
        float    r  = v - fh;
        dh[j] = (unsigned short)(u >> 16);
        dl[j] = (unsigned short)(__builtin_bit_cast(unsigned, r) >> 16);
    }
}

// ---------------------------------------------------------------------------
// k1: GEMM  currents[r][h] = sum_k x[r][k]*W_h[h][k] + b_h[h]
// BM=64, BK=64, 256 threads (4 waves, 1 m-frag each). x-tile 16KB stored as
// 2 subtiles [64 rows][128B], chunk-XOR-swizzled via pre-swizzled source;
// W-tile 16KB linear. Ring-2, 8 glds/thread/tile, vmcnt(8) steady state.
// ---------------------------------------------------------------------------
__device__ __forceinline__ void glds16(const void* src, void* lds) {
    __builtin_amdgcn_global_load_lds(
        (const __attribute__((address_space(1))) void*)src,
        (__attribute__((address_space(3))) void*)lds, 16, 0, 0);
}

__device__ __forceinline__ void splitpair(f32x4 p0, f32x4 p1, short8& hi, short8& lo) {
#pragma unroll
    for (int j = 0; j < 4; ++j) {
        {
            unsigned u  = __builtin_bit_cast(unsigned, p0[j]);
            float    fh = __builtin_bit_cast(float, u & 0xffff0000u);
            float    r  = p0[j] - fh;
            hi[j] = (short)(u >> 16);
            lo[j] = (short)(__builtin_bit_cast(unsigned, r) >> 16);
        }
        {
            unsigned u  = __builtin_bit_cast(unsigned, p1[j]);
            float    fh = __builtin_bit_cast(float, u & 0xffff0000u);
            float    r  = p1[j] - fh;
            hi[j + 4] = (short)(u >> 16);
            lo[j + 4] = (short)(__builtin_bit_cast(unsigned, r) >> 16);
        }
    }
}

// stage x-tile kt: 64 rows x 64 k = 16KB; subtile s = k-half, phys chunk
// (r, pc) holds logical chunk pc ^ (r&7) -> source pre-swizzled.
__device__ __forceinline__ void stage_x64(const float* __restrict__ x, size_t row0,
                                          int kt, int tid, float* sbuf) {
#pragma unroll
    for (int j = 0; j < 4; ++j) {
        int id = j * 256 + tid;                  // 0..1023
        int s  = id >> 9;                        // k-half
        int r  = (id >> 3) & 63;                 // row
        int pc = id & 7;                         // phys chunk in 128B
        int c  = pc ^ (r & 7);                   // logical chunk
        int kbyte = kt * 256 + s * 128 + (c << 4);
        if (kbyte + 16 > K_ * 4) kbyte = 0;      // tail clamp; value * W_pad(0) = 0
        const char* src = (const char*)(x + (row0 + r) * (size_t)K_) + kbyte;
        float* dst = sbuf + (size_t)(id & ~63) * 4;   // wave-uniform base + lane*16B
        glds16(src, dst);
    }
}

// stage W-tile kt: 16KB linear copy.
__device__ __forceinline__ void stage_w64(const unsigned short* __restrict__ wfrag,
                                          int kt, int tid, unsigned short* sbuf) {
#pragma unroll
    for (int j = 0; j < 4; ++j) {
        int id = j * 256 + tid;                  // 0..1023 chunks
        const unsigned short* src = wfrag + (size_t)kt * 8192 + id * 8;
        unsigned short* dst = sbuf + (size_t)(id & ~63) * 8;
        glds16(src, dst);
    }
}

__device__ __forceinline__ void compute64(const float* sbx_, const unsigned short* sbw_,
                                          int lane, int wid, f32x4 (&acc)[4]) {
    const char*   xb = (const char*)sbx_;
    const short8* wb = (const short8*)sbw_;      // hi chunks 0..511, lo 512..1023
    int rloc = wid * 16 + (lane & 15);
    int g2   = ((lane >> 4) & 3) * 2;
#pragma unroll
    for (int kf = 0; kf < 2; ++kf) {
        const char* base = xb + kf * 8192 + rloc * 128;
        int c0 = g2 ^ (rloc & 7);
        int c1 = (g2 + 1) ^ (rloc & 7);
        f32x4 p0 = *(const f32x4*)(base + c0 * 16);
        f32x4 p1 = *(const f32x4*)(base + c1 * 16);
        short8 ah, al;
        splitpair(p0, p1, ah, al);
#pragma unroll
        for (int n = 0; n < 4; ++n) {
            short8 bhf = wb[(n * 2 + kf) * 64 + lane];
            short8 blf = wb[(n * 2 + kf) * 64 + lane + 512];
            acc[n] = __builtin_amdgcn_mfma_f32_16x16x32_bf16(ah, bhf, acc[n], 0, 0, 0);
            acc[n] = __builtin_amdgcn_mfma_f32_16x16x32_bf16(al, bhf, acc[n], 0, 0, 0);
            acc[n] = __builtin_amdgcn_mfma_f32_16x16x32_bf16(ah, blf, acc[n], 0, 0, 0);
        }
    }
}

__global__ __launch_bounds__(256, 2) void gemm_cur(const float* __restrict__ x,
                                                   const unsigned short* __restrict__ wfrag,
                                                   const float* __restrict__ b_h,
                                                   float* __restrict__ cur) {
    __shared__ float          sbx[2][4096];   // 2 x 16KB x-tiles
    __shared__ unsigned short sbw[2][8192];   // 2 x 16KB W-tiles
    int tid  = threadIdx.x;
    int lane = tid & 63;
    int wid  = tid >> 6;             // 0..3
    size_t row0 = (size_t)blockIdx.x * 64;

    float bh4[4];
#pragma unroll
    for (int n = 0; n < 4; ++n) bh4[n] = b_h[n * 16 + (lane & 15)];

    f32x4 acc[4];
#pragma unroll
    for (int n = 0; n < 4; ++n) acc[n] = (f32x4){0.f, 0.f, 0.f, 0.f};

    // prologue: stage tiles 0,1 (8 glds/thread each -> 16 outstanding)
    stage_x64(x, row0, 0, tid, sbx[0]);  stage_w64(wfrag, 0, tid, sbw[0]);
    stage_x64(x, row0, 1, tid, sbx[1]);  stage_w64(wfrag, 1, tid, sbw[1]);

#define GSTEP(T, N)                                                          \
    {                                                                        \
        asm volatile("s_waitcnt vmcnt(" #N ")" ::: "memory");                \
        __builtin_amdgcn_s_barrier();                                        \
        compute64(sbx[(T) & 1], sbw[(T) & 1], lane, wid, acc);               \
        asm volatile("s_waitcnt lgkmcnt(0)" ::: "memory");                   \
        __builtin_amdgcn_s_barrier();                                        \
        if ((T) + 2 < NKT) {                                                 \
            stage_x64(x, row0, (T) + 2, tid, sbx[(T) & 1]);                  \
            stage_w64(wfrag, (T) + 2, tid, sbw[(T) & 1]);                    \
        }                                                                    \
    }
    GSTEP(0, 8)   GSTEP(1, 8)   GSTEP(2, 8)   GSTEP(3, 8)   GSTEP(4, 8)
    GSTEP(5, 8)   GSTEP(6, 8)   GSTEP(7, 8)   GSTEP(8, 8)   GSTEP(9, 8)
    GSTEP(10, 0)
#undef GSTEP

    // epilogue: t-quad layout cur4[(r>>2)*64 + h] (16B stores)
    f32x4* cur4 = (f32x4*)cur;
    size_t r4 = row0 + wid * 16 + ((lane >> 4) & 3) * 4;
#pragma unroll
    for (int n = 0; n < 4; ++n) {
        f32x4 q;
#pragma unroll
        for (int j = 0; j < 4; ++j) q[j] = acc[n][j] + bh4[n];
        cur4[(r4 >> 2) * 64 + n * 16 + (lane & 15)] = q;
    }
}

// ---------------------------------------------------------------------------
// k2: LIF, chunked speculative. One wave per (batch, chunk); lane = neuron.
// t-quad cur layout: lane h loads f32x4 = 4 consecutive t's (coalesced 1KB/op).
// ---------------------------------------------------------------------------
__global__ __launch_bounds__(64) void lif(const float* __restrict__ cur, ull* __restrict__ masks) {
    int b = blockIdx.x & 255;
    int c = blockIdx.x >> 8;
    int h = threadIdx.x;
    int t0 = c * TCL;
    int ts = (c == 0) ? 0 : (t0 - BIL);
    const f32x4* p = (const f32x4*)cur + (((size_t)b * T_ + ts) >> 2) * 64 + h;
    float v = 0.0f;
    int ngb = (t0 - ts) >> 2;          // burn-in groups (0 or 10)
    for (int g = 0; g < ngb; ++g) {
        f32x4 q = p[g * 64];
#pragma unroll
        for (int j = 0; j < 4; ++j) {
            v = (v + q[j]) * 0.5f;
            v = (v >= 1.0f) ? 0.0f : v;
        }
    }
    p += (size_t)ngb * 64;
    ull* mp = masks + (size_t)b * T_ + t0;
#pragma unroll 2
    for (int g = 0; g < TCL / 4; ++g) {
        f32x4 q = p[g * 64];
#pragma unroll
        for (int j = 0; j < 4; ++j) {
            v = (v + q[j]) * 0.5f;
            bool s = (v >= 1.0f);
            ull m = __ballot(s);
            if (h == 0) mp[g * 4 + j] = m;
            v = s ? 0.0f : v;
        }
    }
}

// ---------------------------------------------------------------------------
// k3: fused readout, one block per batch, 512 threads (8 waves).
// TC=5, NC=200; carry and reduce parallelized over (o, group-of-25).
// ---------------------------------------------------------------------------
__global__ __launch_bounds__(512) void readout(const ull* __restrict__ masks,
                                               const float* __restrict__ Wr,
                                               const float* __restrict__ br,
                                               const float* __restrict__ tau,
                                               float* __restrict__ out) {
    __shared__ __align__(16) float wt[64][20];     // wt[h][o]
    __shared__ ull  smask[T_];
    __shared__ __align__(16) float E[NCH][20];
    __shared__ __align__(16) float Sv[NCH][20];
    __shared__ __align__(16) float pacc[NCH][20];
    __shared__ __align__(16) float sScale[20], sBase[20], sBeta[20];
    __shared__ float Pg[8][20], Sst[8][20], part[8][20];

    int tid = threadIdx.x;
    int b   = blockIdx.x;
    for (int i = tid; i < 1280; i += 512) wt[i & 63][i >> 6] = Wr[(size_t)(i >> 6) * 64 + (i & 63)];
    for (int i = tid; i < T_; i += 512) smask[i] = masks[(size_t)b * T_ + i];
    if (tid < 20) {
        float beta = 1.0f / (1.0f + __expf(-tau[tid]));
        sBeta[tid]  = beta;
        sScale[tid] = 1.0f - beta;
        sBase[tid]  = br[tid];
    }
    __syncthreads();

    // phase 1: scanE — items (c, o4), NCH*5 = 1000
    for (int it = tid; it < NCH * 5; it += 512) {
        int o4 = it % 5;
        int c  = it / 5;
        f32x4 beta4  = *(const f32x4*)&sBeta[o4 * 4];
        f32x4 scale4 = *(const f32x4*)&sScale[o4 * 4];
        f32x4 base4  = *(const f32x4*)&sBase[o4 * 4];
        f32x4 v = {0.f, 0.f, 0.f, 0.f};
        const ull* mp = smask + c * TCH;
#pragma unroll
        for (int j = 0; j < TCH; ++j) {
            ull m = mp[j];
            f32x4 a = {0.f, 0.f, 0.f, 0.f};
            while (m) {
                int h = __builtin_ctzll(m);
                m &= (m - 1);
                a += *(const f32x4*)&wt[h][o4 * 4];
            }
            f32x4 q;
#pragma unroll
            for (int jj = 0; jj < 4; ++jj) q[jj] = scale4[jj] * (base4[jj] + a[jj]);
            v = beta4 * v + q;
        }
        *(f32x4*)&E[c][o4 * 4] = v;
    }
    __syncthreads();

    // phase 2a: per-(o, g) partial combine over 25 chunks
    if (tid < 160) {
        int o = tid >> 3, g = tid & 7;
        float beta = sBeta[o];
        float b2 = beta * beta;
        float bp = b2 * b2 * beta;               // beta^5
        float P = 0.0f;
        for (int c = g * 25; c < g * 25 + 25; ++c) P = bp * P + E[c][o];
        Pg[g][o] = P;
    }
    __syncthreads();

    // phase 2b: serial combine of 8 groups per o
    if (tid < 20) {
        int o = tid;
        float beta = sBeta[o];
        float b2 = beta * beta;
        float bp = b2 * b2 * beta;
        float bp25 = 1.0f;
#pragma unroll
        for (int i = 0; i < 25; ++i) bp25 *= bp;
        float s = 0.0f;
        for (int g = 0; g < 8; ++g) { Sst[g][o] = s; s = bp25 * s + Pg[g][o]; }
    }
    __syncthreads();

    // phase 2c: re-scan groups to produce per-chunk starts Sv
    if (tid < 160) {
        int o = tid >> 3, g = tid & 7;
        float beta = sBeta[o];
        float b2 = beta * beta;
        float bp = b2 * b2 * beta;
        float s = Sst[g][o];
        for (int c = g * 25; c < g * 25 + 25; ++c) { Sv[c][o] = s; s = bp * s + E[c][o]; }
    }
    __syncthreads();

    // phase 3: scanSoft — thread c < NCH
    if (tid < NCH) {
        int c = tid;
        float beta[20], v[20], acc[20];
#pragma unroll
        for (int o = 0; o < 20; ++o) {
            beta[o] = sBeta[o];
            v[o]   = Sv[c][o];
            acc[o] = 0.0f;
        }
        int t0 = c * TCH;
        const ull* mp = smask + t0;
#pragma unroll
        for (int j = 0; j < TCH; ++j) {
            int t = t0 + j;
            ull m = mp[j];
            f32x4 a[5];
#pragma unroll
            for (int i = 0; i < 5; ++i) a[i] = (f32x4){0.f, 0.f, 0.f, 0.f};
            while (m) {
                int h = __builtin_ctzll(m);
                m &= (m - 1);
                const f32x4* w4 = (const f32x4*)&wt[h][0];
#pragma unroll
                for (int i = 0; i < 5; ++i) a[i] += w4[i];
            }
#pragma unroll
            for (int o = 0; o < 20; ++o) {
                float q = sScale[o] * (sBase[o] + a[o >> 2][o & 3]);
                v[o] = beta[o] * v[o] + q;
            }
            if (t >= 11) {
                float mx = v[0];
#pragma unroll
                for (int o = 1; o < 20; ++o) mx = fmaxf(mx, v[o]);
                float e[20], ssum = 0.0f;
#pragma unroll
                for (int o = 0; o < 20; ++o) { e[o] = __expf(v[o] - mx); ssum += e[o]; }
                float inv = 1.0f / ssum;
#pragma unroll
                for (int o = 0; o < 20; ++o) acc[o] += e[o] * inv;
            }
        }
#pragma unroll
        for (int o = 0; o < 20; ++o) pacc[c][o] = acc[o];
    }
    __syncthreads();

    // phase 4: reduce — partials then serial-8
    if (tid < 160) {
        int o = tid >> 3, g = tid & 7;
        float s = 0.0f;
        for (int c = g * 25; c < g * 25 + 25; ++c) s += pacc[c][o];
        part[g][o] = s;
    }
    __syncthreads();
    if (tid < 20) {
        float s = 0.0f;
#pragma unroll
        for (int g = 0; g < 8; ++g) s += part[g][tid];
        out[(size_t)b * 20 + tid] = s;
    }
}

// ---------------------------------------------------------------------------
extern "C" void kernel_launch(void* const* d_in, const int* in_sizes, int n_in,
                              void* d_out, int out_size, void* d_ws, size_t ws_size,
                              hipStream_t stream) {
    const float* x   = (const float*)d_in[0];
    const float* W_h = (const float*)d_in[1];
    const float* b_h = (const float*)d_in[2];
    const float* W_r = (const float*)d_in[3];
    const float* b_r = (const float*)d_in[4];
    const float* tau = (const float*)d_in[5];

    char* ws = (char*)d_ws;
    unsigned short* wfrag = (unsigned short*)(ws + OFF_WFRAG);
    float* cur  = (float*)(ws + OFF_CUR);
    ull*   msk  = (ull*)(ws + OFF_MASK);
    float* out  = (float*)d_out;

    wprep<<<22, 256, 0, stream>>>(W_h, wfrag);
    gemm_cur<<<4000, 256, 0, stream>>>(x, wfrag, b_h, cur);
    lif<<<NCL * 256, 64, 0, stream>>>(cur, msk);
    readout<<<256, 512, 0, stream>>>(msk, W_r, b_r, tau, out);
}